// Round 6
// baseline (150.409 us; speedup 1.0000x reference)
//
#include <hip/hip_runtime.h>

// Problem constants: B=1024, D=64, M=3, C=16384
#define B_  1024
#define D_  64
#define M_  3
#define C_  16384

typedef __attribute__((ext_vector_type(8))) short bf16x8;   // MFMA A/B frag
typedef __attribute__((ext_vector_type(4))) float f32x4;    // MFMA acc

// truncating fp32 -> bf16 pack (validated R2-R5): low short = first arg
__device__ __forceinline__ unsigned bfpack2(float lo, float hi) {
    return __builtin_amdgcn_perm(__float_as_uint(hi), __float_as_uint(lo),
                                 0x07060302u);
}
__device__ __forceinline__ bf16x8 pack8(float4 x, float4 y) {
    union { unsigned u[4]; bf16x8 v; } r;
    r.u[0] = bfpack2(x.x, x.y);
    r.u[1] = bfpack2(x.z, x.w);
    r.u[2] = bfpack2(y.x, y.y);
    r.u[3] = bfpack2(y.z, y.w);
    return r.v;
}
__device__ __forceinline__ float fexp2(float x) {   // 2^x, one v_exp_f32
    float r; asm("v_exp_f32 %0, %1" : "=v"(r) : "v"(x)); return r;
}

// ---------------------------------------------------------------------------
// Workspace (floats): ws[0..6144) wsum[2][M][B]; ws[6144..6240) wsred[96]
// ---------------------------------------------------------------------------

__global__ __launch_bounds__(256) void zero_ws(float* __restrict__ ws) {
    int i = blockIdx.x * 256 + threadIdx.x;   // grid 25
    if (i < 6272) ws[i] = 0.0f;
}

// 1-D grid of 1536 blocks, 256 threads (4 waves).
// Decode: xcd = bid&7 keeps all 16 b-blocks of one (c-chunk, m, br) on one
// XCD so the 256 KB cen chunk is L2-shared (12 chunks x 256 KB = 3 MB/XCD).
// Wave owns 64 b-rows: A = features (bf16, reg-resident), B = cen streamed
// fp32->bf16 per 16-row c-tile. D: row = b (fixed per lane slot!), col = c.
// s[t][j] accumulates exp2 over c IN REGISTERS -- no cross-lane op in loop.
__global__ __launch_bounds__(256, 4) void lse_mfma(
    const float* __restrict__ cen0, const float* __restrict__ cen1,
    const float* __restrict__ f0,   const float* __restrict__ f1,
    const float* __restrict__ conc0,const float* __restrict__ conc1,
    float* __restrict__ wsum)       // [2][M][B]
{
    const int bid  = blockIdx.x;
    const int xcd  = bid & 7;
    const int idx  = bid >> 3;          // 0..191
    const int pair = idx >> 4;          // 0..11
    const int bblk = idx & 15;          // 0..15
    const int pid  = xcd * 12 + pair;   // 0..95
    const int cchunk = pid & 15;        // 0..15 (1024 c-rows each)
    const int mbr    = pid >> 4;        // 0..5
    const int br = mbr & 1, m = mbr >> 1;

    const float* __restrict__ cen  = br ? cen1  : cen0;
    const float* __restrict__ ft   = br ? f1    : f0;
    const float* __restrict__ conc = br ? conc1 : conc0;

    const int wv   = threadIdx.x >> 6;
    const int lane = threadIdx.x & 63;
    const int lrow = lane & 15;
    const int lk   = lane >> 4;
    const int wbase = bblk * 64;               // first of wave's 64 b-rows
    const float LOG2E = 1.44269504088896340736f;

    // --- A fragments: 4 row-tiles of features, fp32 -> bf16, resident -----
    bf16x8 af[4][2];
#pragma unroll
    for (int t = 0; t < 4; ++t) {
        const float* fp = ft + (size_t)(wbase + t * 16 + lrow) * D_ + lk * 8;
        float4 x0 = *reinterpret_cast<const float4*>(fp);
        float4 x1 = *reinterpret_cast<const float4*>(fp + 4);
        float4 y0 = *reinterpret_cast<const float4*>(fp + 32);
        float4 y1 = *reinterpret_cast<const float4*>(fp + 36);
        af[t][0] = pack8(x0, x1);   // k = lk*8 .. +7
        af[t][1] = pack8(y0, y1);   // k = 32+lk*8 .. +7
    }

    // --- c-loop: 16 tiles of 16 c-rows (wave chunk = 256 c-rows) ----------
    const int cb = cchunk * 1024 + wv * 256;
    const float* bp = cen  + (size_t)(m * C_ + cb + lrow) * D_ + lk * 8;
    const float* cp = conc + m * C_ + cb + lrow;

    float4 n0 = *reinterpret_cast<const float4*>(bp);
    float4 n1 = *reinterpret_cast<const float4*>(bp + 4);
    float4 n2 = *reinterpret_cast<const float4*>(bp + 32);
    float4 n3 = *reinterpret_cast<const float4*>(bp + 36);
    float  nc = *cp;

    float s[4][4];
#pragma unroll
    for (int t = 0; t < 4; ++t)
#pragma unroll
        for (int j = 0; j < 4; ++j) s[t][j] = 0.0f;

    for (int ct = 0; ct < 16; ++ct) {
        const float4 c0 = n0, c1 = n1, c2 = n2, c3 = n3;
        const float  cc = nc;
        if (ct + 1 < 16) {                    // 1-deep prefetch
            bp += 16 * D_; cp += 16;
            n0 = *reinterpret_cast<const float4*>(bp);
            n1 = *reinterpret_cast<const float4*>(bp + 4);
            n2 = *reinterpret_cast<const float4*>(bp + 32);
            n3 = *reinterpret_cast<const float4*>(bp + 36);
            nc = *cp;
        }
        const bf16x8 bk0 = pack8(c0, c1);     // cen k-half 0
        const bf16x8 bk1 = pack8(c2, c3);     // cen k-half 1
        const float  ic  = LOG2E * __builtin_amdgcn_rcpf(cc);  // per-lane c

        f32x4 a0 = {0.f,0.f,0.f,0.f}, a1 = {0.f,0.f,0.f,0.f};
        f32x4 a2 = {0.f,0.f,0.f,0.f}, a3 = {0.f,0.f,0.f,0.f};
        a0 = __builtin_amdgcn_mfma_f32_16x16x32_bf16(af[0][0], bk0, a0, 0, 0, 0);
        a0 = __builtin_amdgcn_mfma_f32_16x16x32_bf16(af[0][1], bk1, a0, 0, 0, 0);
        a1 = __builtin_amdgcn_mfma_f32_16x16x32_bf16(af[1][0], bk0, a1, 0, 0, 0);
        a1 = __builtin_amdgcn_mfma_f32_16x16x32_bf16(af[1][1], bk1, a1, 0, 0, 0);
        a2 = __builtin_amdgcn_mfma_f32_16x16x32_bf16(af[2][0], bk0, a2, 0, 0, 0);
        a2 = __builtin_amdgcn_mfma_f32_16x16x32_bf16(af[2][1], bk1, a2, 0, 0, 0);
        a3 = __builtin_amdgcn_mfma_f32_16x16x32_bf16(af[3][0], bk0, a3, 0, 0, 0);
        a3 = __builtin_amdgcn_mfma_f32_16x16x32_bf16(af[3][1], bk1, a3, 0, 0, 0);

        // per-lane register accumulation over c: row b is FIXED per (t,lk,j)
#pragma unroll
        for (int j = 0; j < 4; ++j) {
            s[0][j] += fexp2(a0[j] * ic);
            s[1][j] += fexp2(a1[j] * ic);
            s[2][j] += fexp2(a2[j] * ic);
            s[3][j] += fexp2(a3[j] * ic);
        }
    }

    // --- once per wave: butterfly over the 16 c-columns (lrow bits) -------
    __shared__ float lsum[4][64];
#pragma unroll
    for (int t = 0; t < 4; ++t)
#pragma unroll
        for (int j = 0; j < 4; ++j) {
            float v = s[t][j];
            v += __shfl_xor(v, 1);
            v += __shfl_xor(v, 2);
            v += __shfl_xor(v, 4);
            v += __shfl_xor(v, 8);
            s[t][j] = v;
        }
    if (lrow == 0) {
#pragma unroll
        for (int t = 0; t < 4; ++t)
#pragma unroll
            for (int j = 0; j < 4; ++j)
                lsum[wv][t * 16 + lk * 4 + j] = s[t][j];
    }
    __syncthreads();
    if (threadIdx.x < 64) {
        const float v = lsum[0][threadIdx.x] + lsum[1][threadIdx.x]
                      + lsum[2][threadIdx.x] + lsum[3][threadIdx.x];
        atomicAdd(&wsum[(br * M_ + m) * B_ + wbase + threadIdx.x], v);
    }
}

// Per (m,b): term = pos_logit - ln(wsum). Wave-reduce, plain store per wave.
__global__ __launch_bounds__(256) void finish(
    const float* __restrict__ f,    const float* __restrict__ f_I,
    const float* __restrict__ cen0, const float* __restrict__ cen1,
    const float* __restrict__ conc0,const float* __restrict__ conc1,
    const int*   __restrict__ lab0, const int*   __restrict__ lab1,
    const float* __restrict__ wsum, float* __restrict__ wsred)
{
    const int idx = blockIdx.x * 256 + threadIdx.x;   // 0 .. 2*M*B-1
    const int br  = idx / (M_ * B_);
    const int r   = idx - br * (M_ * B_);
    const int m   = r / B_;
    const int b   = r - m * B_;

    const float* cen  = br ? cen1  : cen0;
    const float* conc = br ? conc1 : conc0;
    const int*   lab  = br ? lab1  : lab0;
    const float* ft   = br ? f     : f_I;

    const int c = lab[r];
    const float* cr   = cen + (size_t)(m * C_ + c) * D_;
    const float* frow = ft + (size_t)b * D_;
    float a0 = 0.f, a1 = 0.f, a2 = 0.f, a3 = 0.f;
#pragma unroll
    for (int d = 0; d < D_; d += 4) {
        a0 = fmaf(cr[d + 0], frow[d + 0], a0);
        a1 = fmaf(cr[d + 1], frow[d + 1], a1);
        a2 = fmaf(cr[d + 2], frow[d + 2], a2);
        a3 = fmaf(cr[d + 3], frow[d + 3], a3);
    }
    const float logit = ((a0 + a1) + (a2 + a3)) / conc[(size_t)m * C_ + c];
    float term = logit - __logf(wsum[idx]);

#pragma unroll
    for (int off = 32; off > 0; off >>= 1)
        term += __shfl_down(term, off);
    if ((threadIdx.x & 63) == 0)
        wsred[idx >> 6] = term;            // 96 slots, plain store
}

// Single wave: sum the 96 finish-wave partials, scale, write the output.
__global__ void finalize(const float* __restrict__ wsred,
                         const int*   __restrict__ lb,
                         float* __restrict__ out)
{
    const int t = threadIdx.x;             // 64 threads
    float v = wsred[t];
    if (t < 32) v += wsred[64 + t];
#pragma unroll
    for (int off = 32; off > 0; off >>= 1)
        v += __shfl_down(v, off);
    if (t == 0)
        out[0] = (1.0f / (float)B_) * (float)lb[0] * (-1.0f / (float)M_)
                 * 0.5f * v;
}

extern "C" void kernel_launch(void* const* d_in, const int* in_sizes, int n_in,
                              void* d_out, int out_size, void* d_ws, size_t ws_size,
                              hipStream_t stream) {
    const float* f      = (const float*)d_in[0];
    const float* f_I    = (const float*)d_in[1];
    const float* cen    = (const float*)d_in[2];
    const float* cen_I  = (const float*)d_in[3];
    const float* conc   = (const float*)d_in[4];
    const float* conc_I = (const float*)d_in[5];
    const int*   lab    = (const int*)d_in[6];
    const int*   lab_I  = (const int*)d_in[7];
    const int*   lb     = (const int*)d_in[8];

    float* ws    = (float*)d_ws;
    float* wsum  = ws;                     // [2][M][B] = 6144
    float* wsred = ws + 6144;              // 96
    float* out   = (float*)d_out;

    zero_ws<<<25, 256, 0, stream>>>(ws);

    // branch 0: cen x features_I ; branch 1: cen_I x features
    lse_mfma<<<1536, 256, 0, stream>>>(cen, cen_I, f_I, f, conc, conc_I, wsum);

    finish<<<(2 * M_ * B_) / 256, 256, 0, stream>>>(
        f, f_I, cen, cen_I, conc, conc_I, lab, lab_I, wsum, wsred);

    finalize<<<1, 64, 0, stream>>>(wsred, lb, out);
}